// Round 6
// baseline (237.051 us; speedup 1.0000x reference)
//
#include <hip/hip_runtime.h>
#include <math.h>

#define B_   32
#define C_   32
#define T_   1024
#define NF_  33
#define F2_  66      // NF*2
#define FD_  2112    // C_*F2_
#define NW_  961
#define MLP_ 256
#define HID_ 256
#define HH_  128
#define TN_  32
#define NT_  31      // ceil(961/32)

#define PI_F     3.14159265358979323846f
#define LN2_F    0.69314718055994530942f
#define L2E2_F   2.88539008177792681472f   // 2*log2(e)

typedef unsigned short u16;
typedef unsigned int   u32;
typedef __attribute__((ext_vector_type(8))) short bf16x8;
typedef __attribute__((ext_vector_type(4))) float f32x4;

__device__ __forceinline__ u16 f2bf(float f) {
    u32 u = __float_as_uint(f);
    u = u + 0x7FFFu + ((u >> 16) & 1u);   // RNE
    return (u16)(u >> 16);
}
__device__ __forceinline__ float bf2f(u16 h) {
    return __uint_as_float((u32)h << 16);
}
__device__ __forceinline__ void gload16(const void* g, void* l) {
    __builtin_amdgcn_global_load_lds(
        (const __attribute__((address_space(1))) void*)g,
        (__attribute__((address_space(3))) void*)l, 16, 0, 0);
}
__device__ __forceinline__ float ftanh(float x) {
    float z = __builtin_amdgcn_exp2f(x * L2E2_F);
    return 1.f - 2.f * __builtin_amdgcn_rcpf(z + 1.f);
}
__device__ __forceinline__ float flog1p(float x) {
    return __builtin_amdgcn_logf(1.f + x) * LN2_F;   // v_log_f32 is log2
}
// atan2(y,x)/pi, poly max err ~2e-6 (in pi units)
__device__ __forceinline__ float fatan2pi(float y, float x) {
    const float ay = fabsf(y), ax = fabsf(x);
    const float mn = fminf(ay, ax), mx = fmaxf(ay, ax);
    float t = mn * __builtin_amdgcn_rcpf(mx);
    t = (mx == 0.f) ? 0.f : t;
    const float s = t * t;
    float p = -0.00373098f;
    p = fmaf(p, s,  0.01676008f);
    p = fmaf(p, s, -0.03706162f);
    p = fmaf(p, s,  0.06160679f);
    p = fmaf(p, s, -0.10587735f);
    p = fmaf(p, s,  0.31830265f);
    p *= t;
    p = (ay > ax) ? 0.5f - p : p;
    p = (x < 0.f) ? 1.0f - p : p;
    return copysignf(p, y);
}

// ---------------------------------------------------------------------------
// wconv: fp32 weight matrix -> bf16 hi/lo planes (same layout)
// ---------------------------------------------------------------------------
__global__ __launch_bounds__(256) void wconv_kernel(const float* __restrict__ W,
                                                    u16* __restrict__ WH,
                                                    u16* __restrict__ WL,
                                                    int total) {
    for (int i = blockIdx.x * 256 + threadIdx.x; i < total; i += gridDim.x * 256) {
        const float v = W[i];
        const u16 h = f2bf(v);
        WH[i] = h;
        WL[i] = f2bf(v - bf2f(h));
    }
}

// ---------------------------------------------------------------------------
// softmax(agg) -> wts (single block)
// ---------------------------------------------------------------------------
__global__ __launch_bounds__(256) void softmax_kernel(const float* __restrict__ agg,
                                                      float* __restrict__ wts) {
    const int tid = threadIdx.x;
    __shared__ float red[256];
    float mx = -INFINITY;
    for (int i = tid; i < NW_; i += 256) mx = fmaxf(mx, agg[i]);
    red[tid] = mx; __syncthreads();
    for (int s = 128; s > 0; s >>= 1) {
        if (tid < s) red[tid] = fmaxf(red[tid], red[tid + s]);
        __syncthreads();
    }
    mx = red[0]; __syncthreads();
    float sm = 0.f;
    for (int i = tid; i < NW_; i += 256) sm += expf(agg[i] - mx);
    red[tid] = sm; __syncthreads();
    for (int s = 128; s > 0; s >>= 1) {
        if (tid < s) red[tid] += red[tid + s];
        __syncthreads();
    }
    const float inv = 1.f / red[0];
    for (int i = tid; i < NW_; i += 256) wts[i] = expf(agg[i] - mx) * inv;
}

// ---------------------------------------------------------------------------
// feat v3: SLIDING DFT (unchanged from round 5).
// ---------------------------------------------------------------------------
__global__ __launch_bounds__(256) void feat_kernel(const float* __restrict__ x,
                                                   u32* __restrict__ featP) {
    const int n0 = blockIdx.x * TN_;
    const int cg = blockIdx.y;
    const int bb = blockIdx.z;
    const int tid = threadIdx.x;
    const int tf = tid & 31;     // bin 0..31
    const int c8 = tid >> 5;     // channel-in-group 0..7
    const int c  = cg * 8 + c8;

    __shared__ float2 stab[64];
    __shared__ float xs[8][96];
    __shared__ float basisT[64][68];

    if (tid < 64) {
        float s, cc;
        sincosf(-PI_F * (float)tid / 32.0f, &s, &cc);
        stab[tid] = make_float2(cc, s);
    }
    __syncthreads();
    for (int e = tid; e < 2048; e += 256) {
        const int f = e >> 6, k = e & 63;
        const float2 w = stab[(f * k) & 63];
        basisT[k][2 * f]     = w.x;
        basisT[k][2 * f + 1] = w.y;
    }
    if (tid < 192) {
        const int cs = tid / 24, q = tid % 24;
        const int t0 = n0 + q * 4;
        const float* xb = x + ((size_t)bb * C_ + cg * 8 + cs) * T_;
        float4 v;
        if (t0 + 3 < T_) {
            v = *(const float4*)(xb + t0);
        } else {
            v.x = (t0 + 0 < T_) ? xb[t0 + 0] : 0.f;
            v.y = (t0 + 1 < T_) ? xb[t0 + 1] : 0.f;
            v.z = (t0 + 2 < T_) ? xb[t0 + 2] : 0.f;
            v.w = 0.f;
        }
        *(float4*)&xs[cs][q * 4] = v;
    }
    __syncthreads();

    const size_t rowb = (size_t)bb * NW_;

    // ---- phase 1: bins 0..31, sliding across 32 windows ----
    {
        float re = 0.f, im = 0.f;
#pragma unroll
        for (int k = 0; k < 64; ++k) {
            const float xv = xs[c8][k];
            const float2 w = *(const float2*)&basisT[k][2 * tf];
            re = fmaf(xv, w.x, re);
            im = fmaf(xv, w.y, im);
        }
        const float2 st = stab[tf];
        const float cx = st.x, sx = -st.y;

        for (int j = 0; j < TN_; ++j) {
            const int gn = n0 + j;
            if (gn >= NW_) break;
            const float r   = __builtin_amdgcn_sqrtf(re * re + im * im);
            const float mag = flog1p(r);
            const float ph  = fatan2pi(im, re);
            featP[(rowb + gn) * (FD_ / 2) + 33 * c + tf] =
                (u32)f2bf(mag) | ((u32)f2bf(ph) << 16);
            const float tre = re - xs[c8][j] + xs[c8][j + 64];
            re = tre * cx - im * sx;
            im = tre * sx + im * cx;
        }
    }

    // ---- phase 2: Nyquist bin ----
    {
        const int j   = tid & 31;
        const int c8n = tid >> 5;
        const int gn  = n0 + j;
        if (gn < NW_) {
            float s = 0.f;
#pragma unroll
            for (int k = 0; k < 32; ++k)
                s += xs[c8n][j + 2 * k] - xs[c8n][j + 2 * k + 1];
            const float a = flog1p(fabsf(s));
            const float p = (__float_as_uint(s) >> 31) ? 1.0f : 0.0f;
            featP[(rowb + gn) * (FD_ / 2) + 33 * (cg * 8 + c8n) + 32] =
                (u32)f2bf(a) | ((u32)f2bf(p) << 16);
        }
    }
}

// ---------------------------------------------------------------------------
// gemm3b: depth-2 software pipeline (3 LDS buffers), counted vmcnt, raw
// s_barrier. BM=128 x BN=128, BK=32, 256 threads / 4 waves (2x2 of 64x64).
// Per K-step: {s_waitcnt vmcnt(LPS or 0); s_barrier; stage(t+2); compute(t)}.
//  - wait BEFORE barrier: each wave drains its own buf[t] loads, barrier
//    publishes them to all waves.
//  - barrier BEFORE stage: all waves finished compute(t-1), whose buffer
//    (t-1)%3 == (t+2)%3 is about to be overwritten.
// LDS read swizzle: slot = kc ^ ((row>>1)&3)  -> exact 2-way (free) banks;
// store side pre-swizzles the GLOBAL source chunk (involution, rule 21).
// C = tanh(A @ B^T + bias) * scale. Terms: Ah*Bh + Ah*Bl (+ Al*Bh).
// ---------------------------------------------------------------------------
template<bool HAS_AL, bool OUT_BF16>
__global__ __launch_bounds__(256, 2) void gemm3b_kernel(
        const u16* __restrict__ AH, const u16* __restrict__ AL,
        const u16* __restrict__ BH, const u16* __restrict__ BL,
        const float* __restrict__ bias, float scale,
        u16* __restrict__ outH, u16* __restrict__ outL, float* __restrict__ outF,
        int Mvalid, int Nstride, int Kd) {
    constexpr int STEPB = HAS_AL ? 32768 : 24576;   // bytes per K-step
    constexpr int OFFAL = 8192;
    constexpr int OFFB  = HAS_AL ? 16384 : 8192;
    __shared__ char lds[3 * STEPB];

    const int bm = blockIdx.x, bn = blockIdx.y;
    const int tid = threadIdx.x;
    const int lane = tid & 63, w = tid >> 6;
    const int wr = w >> 1, wc = w & 1;          // 2x2 waves of 64x64
    const int m0 = bm * 128, n0 = bn * 128;

    f32x4 acc[4][4];
#pragma unroll
    for (int i = 0; i < 4; ++i)
#pragma unroll
        for (int j = 0; j < 4; ++j) acc[i][j] = (f32x4){0.f, 0.f, 0.f, 0.f};

    const size_t rs = (size_t)Kd * 2;
    const char* gAH = (const char*)AH + (size_t)m0 * rs;
    const char* gAL = (const char*)AL + (size_t)m0 * rs;
    const char* gBH = (const char*)BH + (size_t)n0 * rs;
    const char* gBL = (const char*)BL + (size_t)n0 * rs;

    const int nt = Kd >> 5;   // K-steps of 32 (>=2 for all our layers)

    // one 16B chunk: LDS linear slot idx (0..511), global chunk pre-swizzled
    auto st1 = [&](const char* g, char* l, int idx) {
        const int row = idx >> 2, slot = idx & 3;
        const int kc = slot ^ ((row >> 1) & 3);
        gload16(g + (size_t)row * rs + (size_t)(kc << 4), l + idx * 16);
    };
    auto stage = [&](int buf, int t) {
        const size_t k0b = (size_t)t << 6;      // t*64 bytes
        char* lb = lds + buf * STEPB;
        st1(gAH + k0b, lb, tid);
        st1(gAH + k0b, lb, tid + 256);
        if constexpr (HAS_AL) {
            st1(gAL + k0b, lb + OFFAL, tid);
            st1(gAL + k0b, lb + OFFAL, tid + 256);
        }
        st1(gBH + k0b, lb + OFFB, tid);
        st1(gBH + k0b, lb + OFFB, tid + 256);
        st1(gBL + k0b, lb + OFFB + 8192, tid);
        st1(gBL + k0b, lb + OFFB + 8192, tid + 256);
    };

    // read-side fragment addressing (swizzle invariant under row += 16)
    const int r0a = wr * 64 + (lane & 15);
    const int r0b = wc * 64 + (lane & 15);
    const int qa  = lane >> 4;
    const int abase = r0a * 64 + ((qa ^ ((r0a >> 1) & 3)) << 4);
    const int bbase = r0b * 64 + ((qa ^ ((r0b >> 1) & 3)) << 4);

    stage(0, 0);
    stage(1, 1);

    int cur = 0;
    for (int t = 0; t < nt; ++t) {
        // wait buf[t] complete: in-flight = stage(t) (+ stage(t+1) if exists)
        if (t + 1 < nt) {
            if constexpr (HAS_AL)
                asm volatile("s_waitcnt vmcnt(8)" ::: "memory");
            else
                asm volatile("s_waitcnt vmcnt(6)" ::: "memory");
        } else {
            asm volatile("s_waitcnt vmcnt(0)" ::: "memory");
        }
        __builtin_amdgcn_sched_barrier(0);
        __builtin_amdgcn_s_barrier();
        asm volatile("" ::: "memory");

        int pf = cur + 2; if (pf >= 3) pf -= 3;
        if (t + 2 < nt) stage(pf, t + 2);

        const char* lb    = lds + cur * STEPB;
        const char* alBuf = lb + OFFAL;
        const char* bhBuf = lb + OFFB;
        const char* blBuf = lb + OFFB + 8192;

        bf16x8 ah[4], al[4], bh[4], bl[4];
#pragma unroll
        for (int f = 0; f < 4; ++f) {
            ah[f] = *(const bf16x8*)(lb + abase + f * 1024);
            if constexpr (HAS_AL) al[f] = *(const bf16x8*)(alBuf + abase + f * 1024);
            bh[f] = *(const bf16x8*)(bhBuf + bbase + f * 1024);
            bl[f] = *(const bf16x8*)(blBuf + bbase + f * 1024);
        }
#pragma unroll
        for (int fm = 0; fm < 4; ++fm)
#pragma unroll
            for (int fn = 0; fn < 4; ++fn) {
                acc[fm][fn] = __builtin_amdgcn_mfma_f32_16x16x32_bf16(ah[fm], bh[fn], acc[fm][fn], 0, 0, 0);
                acc[fm][fn] = __builtin_amdgcn_mfma_f32_16x16x32_bf16(ah[fm], bl[fn], acc[fm][fn], 0, 0, 0);
                if constexpr (HAS_AL)
                    acc[fm][fn] = __builtin_amdgcn_mfma_f32_16x16x32_bf16(al[fm], bh[fn], acc[fm][fn], 0, 0, 0);
            }
        ++cur; if (cur >= 3) cur -= 3;
    }

    float bv[4];
#pragma unroll
    for (int fn = 0; fn < 4; ++fn) bv[fn] = bias[n0 + wc * 64 + fn * 16 + (lane & 15)];
#pragma unroll
    for (int fm = 0; fm < 4; ++fm) {
        const int rbase = m0 + wr * 64 + fm * 16 + (lane >> 4) * 4;
#pragma unroll
        for (int fn = 0; fn < 4; ++fn) {
            const int col = n0 + wc * 64 + fn * 16 + (lane & 15);
#pragma unroll
            for (int r = 0; r < 4; ++r) {
                const int row = rbase + r;
                if (row < Mvalid) {
                    const float v = ftanh(acc[fm][fn][r] + bv[fn]) * scale;
                    if constexpr (OUT_BF16) {
                        const u16 h = f2bf(v);
                        outH[(size_t)row * Nstride + col] = h;
                        outL[(size_t)row * Nstride + col] = f2bf(v - bf2f(h));
                    } else {
                        outF[(size_t)row * Nstride + col] = v;
                    }
                }
            }
        }
    }
}

// ---------------------------------------------------------------------------
// out_reduce: per b, out[b] = sum_n (h2[b,n,:]·Wout + bout) * wts[n]
// ---------------------------------------------------------------------------
__global__ __launch_bounds__(256) void out_reduce_kernel(const float* __restrict__ h2,
                                                         const float* __restrict__ Wout,
                                                         const float* __restrict__ bout,
                                                         const float* __restrict__ wts,
                                                         float* __restrict__ out) {
    const int bb = blockIdx.x;
    const int tid = threadIdx.x;
    __shared__ float wsh[HH_];
    __shared__ float red[256];
    if (tid < HH_) wsh[tid] = Wout[tid];
    __syncthreads();
    const float bo = bout[0];
    float acc = 0.f;
    for (int n = tid; n < NW_; n += 256) {
        const float* row = h2 + ((size_t)bb * NW_ + n) * HH_;
        float dot = 0.f;
#pragma unroll
        for (int j = 0; j < HH_; j += 4) {
            const float4 v = *(const float4*)(row + j);
            dot += v.x * wsh[j] + v.y * wsh[j + 1] + v.z * wsh[j + 2] + v.w * wsh[j + 3];
        }
        acc += (dot + bo) * wts[n];
    }
    red[tid] = acc;
    __syncthreads();
    for (int s = 128; s > 0; s >>= 1) {
        if (tid < s) red[tid] += red[tid + s];
        __syncthreads();
    }
    if (tid == 0) out[bb] = red[0];
}

// ---------------------------------------------------------------------------
extern "C" void kernel_launch(void* const* d_in, const int* in_sizes, int n_in,
                              void* d_out, int out_size, void* d_ws, size_t ws_size,
                              hipStream_t stream) {
    const float* x    = (const float*)d_in[0];
    const float* Wp   = (const float*)d_in[1];
    const float* bp   = (const float*)d_in[2];
    const float* W1   = (const float*)d_in[3];
    const float* b1   = (const float*)d_in[4];
    const float* W2   = (const float*)d_in[5];
    const float* b2   = (const float*)d_in[6];
    const float* Wout = (const float*)d_in[7];
    const float* bout = (const float*)d_in[8];
    const float* agg  = (const float*)d_in[9];
    float* out = (float*)d_out;

    char* wsb = (char*)d_ws;
    size_t off = 0;
    auto ra = [](size_t b) { return (b + 255) & ~(size_t)255; };
    auto alloc = [&](size_t bytes) -> char* {
        char* p = wsb + off;
        off += ra(bytes);
        return p;
    };

    u16* WpH = (u16*)alloc((size_t)MLP_ * FD_ * 2);
    u16* WpL = (u16*)alloc((size_t)MLP_ * FD_ * 2);
    u16* W1H = (u16*)alloc((size_t)HID_ * MLP_ * 2);
    u16* W1L = (u16*)alloc((size_t)HID_ * MLP_ * 2);
    u16* W2H = (u16*)alloc((size_t)HH_ * HID_ * 2);
    u16* W2L = (u16*)alloc((size_t)HH_ * HID_ * 2);
    float* wts = (float*)alloc((size_t)NW_ * 4);

    const size_t fixed = off;
    int NB = 32;
    for (;;) {
        const size_t M = (size_t)NB * NW_;
        const size_t Mp = ((M + 127) / 128) * 128;
        const size_t need = ra(Mp * FD_ * 2) +        // featH
                            4 * ra(Mp * 256 * 2) +    // projH/L, h1H/L
                            ra(Mp * 128 * 4);         // h2
        if (fixed + need <= ws_size || NB == 1) break;
        NB >>= 1;
    }
    const size_t Mmax  = (size_t)NB * NW_;
    const size_t MpMax = ((Mmax + 127) / 128) * 128;
    u16* featH = (u16*)alloc(MpMax * FD_ * 2);
    u16* projH = (u16*)alloc(MpMax * 256 * 2);
    u16* projL = (u16*)alloc(MpMax * 256 * 2);
    u16* h1H   = (u16*)alloc(MpMax * 256 * 2);
    u16* h1L   = (u16*)alloc(MpMax * 256 * 2);
    float* h2  = (float*)alloc(MpMax * 128 * 4);

    wconv_kernel<<<dim3(128), dim3(256), 0, stream>>>(Wp, WpH, WpL, MLP_ * FD_);
    wconv_kernel<<<dim3(32),  dim3(256), 0, stream>>>(W1, W1H, W1L, HID_ * MLP_);
    wconv_kernel<<<dim3(16),  dim3(256), 0, stream>>>(W2, W2H, W2L, HH_ * HID_);
    softmax_kernel<<<dim3(1), dim3(256), 0, stream>>>(agg, wts);

    for (int b0 = 0; b0 < B_; b0 += NB) {
        const int nb = (B_ - b0 < NB) ? (B_ - b0) : NB;
        const int M = nb * NW_;
        const int Mp = ((M + 127) / 128) * 128;

        feat_kernel<<<dim3(NT_, 4, nb), dim3(256), 0, stream>>>(
            x + (size_t)b0 * C_ * T_, (u32*)featH);

        // proj: tanh(feat @ Wp^T + bp) * pi   (2-term split, K=2112)
        gemm3b_kernel<false, true><<<dim3(Mp / 128, 2), dim3(256), 0, stream>>>(
            featH, nullptr, WpH, WpL, bp, PI_F, projH, projL, nullptr, M, 256, FD_);

        // h1: tanh(proj @ W1^T + b1)          (3-term split, K=256)
        gemm3b_kernel<true, true><<<dim3(Mp / 128, 2), dim3(256), 0, stream>>>(
            projH, projL, W1H, W1L, b1, 1.0f, h1H, h1L, nullptr, M, 256, MLP_);

        // h2: tanh(h1 @ W2^T + b2), fp32 out  (3-term split, K=256)
        gemm3b_kernel<true, false><<<dim3(Mp / 128, 1), dim3(256), 0, stream>>>(
            h1H, h1L, W2H, W2L, b2, 1.0f, nullptr, nullptr, h2, M, 128, HID_);

        out_reduce_kernel<<<dim3(nb), dim3(256), 0, stream>>>(
            h2, Wout, bout, wts, out + b0);
    }
}